// Round 1
// baseline (205.250 us; speedup 1.0000x reference)
//
#include <hip/hip_runtime.h>
#include <stdint.h>

#define NROWS 8192
#define HALF_N 4096
#define DIM 512
#define INV_TEMP 2.0f

typedef __bf16 bf16x8 __attribute__((ext_vector_type(8)));
typedef float f32x4 __attribute__((ext_vector_type(4)));

__device__ __forceinline__ unsigned f2bf(float f) {
  unsigned u = __float_as_uint(f);
  unsigned r = 0x7FFFu + ((u >> 16) & 1u);
  return (u + r) >> 16;  // round-to-nearest-even bf16 bits
}

// global -> LDS direct copy, 16B per lane; LDS dest is wave-uniform base + lane*16
__device__ __forceinline__ void gload_lds16(const unsigned short* g, unsigned short* l) {
  __builtin_amdgcn_global_load_lds(
      (const __attribute__((address_space(1))) unsigned int*)(uintptr_t)g,
      (__attribute__((address_space(3))) unsigned int*)(uint32_t)(uintptr_t)l,
      16, 0, 0);
}

// One wave per row: sumsq -> rsqrt -> bf16 store. Also zeroes sumexp (ws is poisoned each call).
__global__ void __launch_bounds__(256) k_normalize(const float* __restrict__ zi,
                                                   const float* __restrict__ zj,
                                                   unsigned short* __restrict__ zn,
                                                   float* __restrict__ sumexp) {
  int tid = threadIdx.x;
  int gid = blockIdx.x * 256 + tid;
  if (gid < NROWS) sumexp[gid] = 0.0f;
  int wave = tid >> 6, lane = tid & 63;
  int row = blockIdx.x * 4 + wave;
  const float* src = (row < HALF_N) ? (zi + (size_t)row * DIM)
                                    : (zj + (size_t)(row - HALF_N) * DIM);
  const float4* s4 = (const float4*)src;
  float4 a = s4[lane * 2];
  float4 b = s4[lane * 2 + 1];
  float ss = a.x * a.x + a.y * a.y + a.z * a.z + a.w * a.w +
             b.x * b.x + b.y * b.y + b.z * b.z + b.w * b.w;
#pragma unroll
  for (int off = 32; off > 0; off >>= 1) ss += __shfl_xor(ss, off, 64);
  float nrm = fmaxf(sqrtf(ss), 1e-8f);
  float inv = 1.0f / nrm;
  unsigned w0 = f2bf(a.x * inv) | (f2bf(a.y * inv) << 16);
  unsigned w1 = f2bf(a.z * inv) | (f2bf(a.w * inv) << 16);
  unsigned w2 = f2bf(b.x * inv) | (f2bf(b.y * inv) << 16);
  unsigned w3 = f2bf(b.z * inv) | (f2bf(b.w * inv) << 16);
  uint4 o;
  o.x = w0; o.y = w1; o.z = w2; o.w = w3;
  *((uint4*)(zn + (size_t)row * DIM + lane * 8)) = o;
}

// 128x128 output tile per block; flash-style row-sum of exp(sim) epilogue + pos extraction.
__global__ void __launch_bounds__(256) k_simsum(const unsigned short* __restrict__ zn,
                                                float* __restrict__ sumexp,
                                                float* __restrict__ posv) {
  __shared__ __align__(16) unsigned short As[128 * 32];  // 8 KB
  __shared__ __align__(16) unsigned short Bs[128 * 32];  // 8 KB
  int tid = threadIdx.x;
  int wave = tid >> 6, lane = tid & 63;
  int tm = blockIdx.x >> 6, tn = blockIdx.x & 63;
  int rowBase = tm * 128, colBase = tn * 128;
  int wr = (wave >> 1) * 64, wc = (wave & 1) * 64;  // wave's 64x64 quadrant
  int r15 = lane & 15, q = lane >> 4;

  // staging: wave w copies 32 rows of A-tile and B-tile; 16B/lane; 4 lanes per 32-elem row
  int rA = wave * 32 + (lane >> 2);
  int c8 = (lane & 3) * 8;
  const unsigned short* gA0 = zn + (size_t)(rowBase + rA) * DIM + c8;
  const unsigned short* gA1 = gA0 + 16 * DIM;
  const unsigned short* gB0 = zn + (size_t)(colBase + rA) * DIM + c8;
  const unsigned short* gB1 = gB0 + 16 * DIM;
  unsigned short* lA0 = As + wave * 1024;
  unsigned short* lA1 = lA0 + 512;
  unsigned short* lB0 = Bs + wave * 1024;
  unsigned short* lB1 = lB0 + 512;

  f32x4 acc[4][4];
#pragma unroll
  for (int i = 0; i < 4; i++)
#pragma unroll
    for (int j = 0; j < 4; j++) acc[i][j] = (f32x4){0.f, 0.f, 0.f, 0.f};

  const bf16x8* Av = (const bf16x8*)As;
  const bf16x8* Bv = (const bf16x8*)Bs;
  int aIdx0 = (wr + r15) * 4 + q;  // + 64 per 16-row step
  int bIdx0 = (wc + r15) * 4 + q;

  for (int k0 = 0; k0 < DIM; k0 += 32) {
    __syncthreads();  // previous-iter LDS consumers done
    gload_lds16(gA0, lA0);
    gload_lds16(gA1, lA1);
    gload_lds16(gB0, lB0);
    gload_lds16(gB1, lB1);
    gA0 += 32; gA1 += 32; gB0 += 32; gB1 += 32;
    __syncthreads();  // staging complete
    bf16x8 af[4], bfr[4];
#pragma unroll
    for (int i = 0; i < 4; i++) af[i] = Av[aIdx0 + i * 64];
#pragma unroll
    for (int j = 0; j < 4; j++) bfr[j] = Bv[bIdx0 + j * 64];
#pragma unroll
    for (int i = 0; i < 4; i++)
#pragma unroll
      for (int j = 0; j < 4; j++)
        acc[i][j] = __builtin_amdgcn_mfma_f32_16x16x32_bf16(af[i], bfr[j], acc[i][j], 0, 0, 0);
  }

  // Epilogue: C/D layout col=lane&15, row=q*4+reg. Scale by 1/TEMP, exp, mask diag,
  // capture pos (col == row^4096), per-row reduce across the 16 col-lanes, atomic add.
  float rs[16];
#pragma unroll
  for (int t = 0; t < 16; t++) rs[t] = 0.f;
  int gr0 = rowBase + wr + q * 4;
  int gc0 = colBase + wc + r15;
#pragma unroll
  for (int i = 0; i < 4; i++) {
#pragma unroll
    for (int j = 0; j < 4; j++) {
#pragma unroll
      for (int r = 0; r < 4; r++) {
        float s = acc[i][j][r] * INV_TEMP;
        int gr = gr0 + i * 16 + r;
        int gc = gc0 + j * 16;
        if (gc == (gr ^ HALF_N)) posv[gr] = s;  // unique (row,col) across grid -> race-free
        float e = __expf(s);
        if (gc == gr) e = 0.f;  // exclude diagonal
        rs[i * 4 + r] += e;
      }
    }
  }
#pragma unroll
  for (int off = 1; off < 16; off <<= 1) {
#pragma unroll
    for (int t = 0; t < 16; t++) rs[t] += __shfl_xor(rs[t], off, 64);
  }
  if (r15 == 0) {
#pragma unroll
    for (int i = 0; i < 4; i++)
#pragma unroll
      for (int r = 0; r < 4; r++)
        atomicAdd(&sumexp[gr0 + i * 16 + r], rs[i * 4 + r]);
  }
}

__global__ void __launch_bounds__(512) k_final(const float* __restrict__ sumexp,
                                               const float* __restrict__ posv,
                                               float* __restrict__ out) {
  __shared__ float red[8];
  int tid = threadIdx.x;
  float p = 0.f;
  for (int r = tid; r < NROWS; r += 512) p += __logf(sumexp[r]) - posv[r];
#pragma unroll
  for (int off = 32; off > 0; off >>= 1) p += __shfl_xor(p, off, 64);
  int wv = tid >> 6, ln = tid & 63;
  if (ln == 0) red[wv] = p;
  __syncthreads();
  if (tid == 0) {
    float t = 0.f;
    for (int w = 0; w < 8; w++) t += red[w];
    out[0] = t / (float)NROWS;
  }
}

extern "C" void kernel_launch(void* const* d_in, const int* in_sizes, int n_in,
                              void* d_out, int out_size, void* d_ws, size_t ws_size,
                              hipStream_t stream) {
  const float* zi = (const float*)d_in[0];
  const float* zj = (const float*)d_in[1];
  unsigned short* zn = (unsigned short*)d_ws;                         // 8192*512 bf16 = 8 MB
  float* sumexp = (float*)((char*)d_ws + (size_t)NROWS * DIM * 2);    // 32 KB
  float* posv = sumexp + NROWS;                                       // 32 KB
  float* out = (float*)d_out;

  hipLaunchKernelGGL(k_normalize, dim3(2048), dim3(256), 0, stream, zi, zj, zn, sumexp);
  hipLaunchKernelGGL(k_simsum, dim3(4096), dim3(256), 0, stream, zn, sumexp, posv);
  hipLaunchKernelGGL(k_final, dim3(1), dim3(512), 0, stream, sumexp, posv, out);
}

// Round 2
// 200.372 us; speedup vs baseline: 1.0243x; 1.0243x over previous
//
#include <hip/hip_runtime.h>
#include <stdint.h>

#define NROWS 8192
#define HALF_N 4096
#define DIM 512
#define INV_TEMP 2.0f

typedef __bf16 bf16x8 __attribute__((ext_vector_type(8)));
typedef float f32x4 __attribute__((ext_vector_type(4)));

__device__ __forceinline__ unsigned f2bf(float f) {
  unsigned u = __float_as_uint(f);
  unsigned r = 0x7FFFu + ((u >> 16) & 1u);
  return (u + r) >> 16;  // round-to-nearest-even bf16 bits
}

// global -> LDS direct copy, 16B per lane; LDS dest is wave-uniform base + lane*16
__device__ __forceinline__ void gload_lds16(const unsigned short* g, unsigned short* l) {
  __builtin_amdgcn_global_load_lds(
      (const __attribute__((address_space(1))) unsigned int*)(uintptr_t)g,
      (__attribute__((address_space(3))) unsigned int*)(uint32_t)(uintptr_t)l,
      16, 0, 0);
}

// One wave per row: sumsq -> rsqrt -> bf16 store. Also zeroes sumexp (ws is poisoned each call).
__global__ void __launch_bounds__(256) k_normalize(const float* __restrict__ zi,
                                                   const float* __restrict__ zj,
                                                   unsigned short* __restrict__ zn,
                                                   float* __restrict__ sumexp) {
  int tid = threadIdx.x;
  int gid = blockIdx.x * 256 + tid;
  if (gid < NROWS) sumexp[gid] = 0.0f;
  int wave = tid >> 6, lane = tid & 63;
  int row = blockIdx.x * 4 + wave;
  const float* src = (row < HALF_N) ? (zi + (size_t)row * DIM)
                                    : (zj + (size_t)(row - HALF_N) * DIM);
  const float4* s4 = (const float4*)src;
  float4 a = s4[lane];        // elements lane*4 .. lane*4+3   (fully coalesced)
  float4 b = s4[lane + 64];   // elements 256+lane*4 ..        (fully coalesced)
  float ss = a.x * a.x + a.y * a.y + a.z * a.z + a.w * a.w +
             b.x * b.x + b.y * b.y + b.z * b.z + b.w * b.w;
#pragma unroll
  for (int off = 32; off > 0; off >>= 1) ss += __shfl_xor(ss, off, 64);
  float nrm = fmaxf(sqrtf(ss), 1e-8f);
  float inv = 1.0f / nrm;
  uint2 oa, ob;
  oa.x = f2bf(a.x * inv) | (f2bf(a.y * inv) << 16);
  oa.y = f2bf(a.z * inv) | (f2bf(a.w * inv) << 16);
  ob.x = f2bf(b.x * inv) | (f2bf(b.y * inv) << 16);
  ob.y = f2bf(b.z * inv) | (f2bf(b.w * inv) << 16);
  unsigned short* dst = zn + (size_t)row * DIM;
  *((uint2*)(dst + lane * 4)) = oa;
  *((uint2*)(dst + 256 + lane * 4)) = ob;
}

// 128x128 output tile per block; flash-style row-sum of exp(sim) epilogue + pos extraction.
// LDS layout is XOR-swizzled at 16B-granule level: granule `pos` of row r holds global
// k-chunk `pos ^ ((r>>1)&3)` -> fragment reads are 2-way-conflict (free) instead of 8-way.
__global__ void __launch_bounds__(256) k_simsum(const unsigned short* __restrict__ zn,
                                                float* __restrict__ sumexp,
                                                float* __restrict__ posv) {
  __shared__ __align__(16) unsigned short As[128 * 32];  // 8 KB
  __shared__ __align__(16) unsigned short Bs[128 * 32];  // 8 KB
  int tid = threadIdx.x;
  int wave = tid >> 6, lane = tid & 63;
  int tm = blockIdx.x >> 6, tn = blockIdx.x & 63;
  int rowBase = tm * 128, colBase = tn * 128;
  int wr = (wave >> 1) * 64, wc = (wave & 1) * 64;  // wave's 64x64 quadrant
  int r15 = lane & 15, q = lane >> 4;

  // staging: wave w copies 32 rows of A-tile and B-tile; 16B/lane; 4 lanes per 32-elem row.
  // Source k-chunk XOR-swizzled by ((row>>1)&3); invariant under row+16 so gA1/gB1 share it.
  int rA = wave * 32 + (lane >> 2);
  int swzS = (rA >> 1) & 3;
  int c8 = ((lane & 3) ^ swzS) * 8;
  const unsigned short* gA0 = zn + (size_t)(rowBase + rA) * DIM + c8;
  const unsigned short* gA1 = gA0 + 16 * DIM;
  const unsigned short* gB0 = zn + (size_t)(colBase + rA) * DIM + c8;
  const unsigned short* gB1 = gB0 + 16 * DIM;
  unsigned short* lA0 = As + wave * 1024;
  unsigned short* lA1 = lA0 + 512;
  unsigned short* lB0 = Bs + wave * 1024;
  unsigned short* lB1 = lB0 + 512;

  f32x4 acc[4][4];
#pragma unroll
  for (int i = 0; i < 4; i++)
#pragma unroll
    for (int j = 0; j < 4; j++) acc[i][j] = (f32x4){0.f, 0.f, 0.f, 0.f};

  const bf16x8* Av = (const bf16x8*)As;
  const bf16x8* Bv = (const bf16x8*)Bs;
  int swzR = (r15 >> 1) & 3;                 // == ((wr+i*16+r15)>>1)&3 for all i
  int aIdx0 = (wr + r15) * 4 + (q ^ swzR);   // + 64 per 16-row step
  int bIdx0 = (wc + r15) * 4 + (q ^ swzR);

  for (int k0 = 0; k0 < DIM; k0 += 32) {
    __syncthreads();  // previous-iter LDS consumers done
    gload_lds16(gA0, lA0);
    gload_lds16(gA1, lA1);
    gload_lds16(gB0, lB0);
    gload_lds16(gB1, lB1);
    gA0 += 32; gA1 += 32; gB0 += 32; gB1 += 32;
    __syncthreads();  // staging complete
    bf16x8 af[4], bfr[4];
#pragma unroll
    for (int i = 0; i < 4; i++) af[i] = Av[aIdx0 + i * 64];
#pragma unroll
    for (int j = 0; j < 4; j++) bfr[j] = Bv[bIdx0 + j * 64];
#pragma unroll
    for (int i = 0; i < 4; i++)
#pragma unroll
      for (int j = 0; j < 4; j++)
        acc[i][j] = __builtin_amdgcn_mfma_f32_16x16x32_bf16(af[i], bfr[j], acc[i][j], 0, 0, 0);
  }

  // Epilogue: C/D layout col=lane&15, row=q*4+reg. Scale by 1/TEMP, exp, mask diag,
  // capture pos (col == row^4096), per-row reduce across the 16 col-lanes, atomic add.
  float rs[16];
#pragma unroll
  for (int t = 0; t < 16; t++) rs[t] = 0.f;
  int gr0 = rowBase + wr + q * 4;
  int gc0 = colBase + wc + r15;
#pragma unroll
  for (int i = 0; i < 4; i++) {
#pragma unroll
    for (int j = 0; j < 4; j++) {
#pragma unroll
      for (int r = 0; r < 4; r++) {
        float s = acc[i][j][r] * INV_TEMP;
        int gr = gr0 + i * 16 + r;
        int gc = gc0 + j * 16;
        if (gc == (gr ^ HALF_N)) posv[gr] = s;  // unique (row,col) across grid -> race-free
        float e = __expf(s);
        if (gc == gr) e = 0.f;  // exclude diagonal
        rs[i * 4 + r] += e;
      }
    }
  }
#pragma unroll
  for (int off = 1; off < 16; off <<= 1) {
#pragma unroll
    for (int t = 0; t < 16; t++) rs[t] += __shfl_xor(rs[t], off, 64);
  }
  if (r15 == 0) {
#pragma unroll
    for (int i = 0; i < 4; i++)
#pragma unroll
      for (int r = 0; r < 4; r++)
        atomicAdd(&sumexp[gr0 + i * 16 + r], rs[i * 4 + r]);
  }
}

__global__ void __launch_bounds__(1024) k_final(const float* __restrict__ sumexp,
                                                const float* __restrict__ posv,
                                                float* __restrict__ out) {
  __shared__ float red[16];
  int tid = threadIdx.x;
  const float4* se4 = (const float4*)sumexp;
  const float4* pv4 = (const float4*)posv;
  float p = 0.f;
#pragma unroll
  for (int c = 0; c < 2; c++) {
    float4 se = se4[tid * 2 + c];
    float4 pv = pv4[tid * 2 + c];
    p += (__logf(se.x) - pv.x) + (__logf(se.y) - pv.y) +
         (__logf(se.z) - pv.z) + (__logf(se.w) - pv.w);
  }
#pragma unroll
  for (int off = 32; off > 0; off >>= 1) p += __shfl_xor(p, off, 64);
  int wv = tid >> 6, ln = tid & 63;
  if (ln == 0) red[wv] = p;
  __syncthreads();
  if (tid == 0) {
    float t = 0.f;
    for (int w = 0; w < 16; w++) t += red[w];
    out[0] = t / (float)NROWS;
  }
}

extern "C" void kernel_launch(void* const* d_in, const int* in_sizes, int n_in,
                              void* d_out, int out_size, void* d_ws, size_t ws_size,
                              hipStream_t stream) {
  const float* zi = (const float*)d_in[0];
  const float* zj = (const float*)d_in[1];
  unsigned short* zn = (unsigned short*)d_ws;                         // 8192*512 bf16 = 8 MB
  float* sumexp = (float*)((char*)d_ws + (size_t)NROWS * DIM * 2);    // 32 KB
  float* posv = sumexp + NROWS;                                       // 32 KB
  float* out = (float*)d_out;

  hipLaunchKernelGGL(k_normalize, dim3(2048), dim3(256), 0, stream, zi, zj, zn, sumexp);
  hipLaunchKernelGGL(k_simsum, dim3(4096), dim3(256), 0, stream, zn, sumexp, posv);
  hipLaunchKernelGGL(k_final, dim3(1), dim3(1024), 0, stream, sumexp, posv, out);
}

// Round 3
// 114.573 us; speedup vs baseline: 1.7914x; 1.7489x over previous
//
#include <hip/hip_runtime.h>
#include <stdint.h>

#define NROWS 8192
#define HALF_N 4096
#define DIM 512
#define INV_TEMP 2.0f

typedef __bf16 bf16x8 __attribute__((ext_vector_type(8)));
typedef float f32x4 __attribute__((ext_vector_type(4)));

__device__ __forceinline__ unsigned f2bf(float f) {
  unsigned u = __float_as_uint(f);
  unsigned r = 0x7FFFu + ((u >> 16) & 1u);
  return (u + r) >> 16;  // round-to-nearest-even bf16 bits
}

// global -> LDS direct copy, 16B per lane; LDS dest is wave-uniform base + lane*16
__device__ __forceinline__ void gload_lds16(const unsigned short* g, unsigned short* l) {
  __builtin_amdgcn_global_load_lds(
      (const __attribute__((address_space(1))) unsigned int*)(uintptr_t)g,
      (__attribute__((address_space(3))) unsigned int*)(uint32_t)(uintptr_t)l,
      16, 0, 0);
}

// One wave per row: sumsq -> rsqrt -> bf16 store. Also zeroes sumexp (ws is poisoned each call).
__global__ void __launch_bounds__(256) k_normalize(const float* __restrict__ zi,
                                                   const float* __restrict__ zj,
                                                   unsigned short* __restrict__ zn,
                                                   float* __restrict__ sumexp) {
  int tid = threadIdx.x;
  int gid = blockIdx.x * 256 + tid;
  if (gid < NROWS) sumexp[gid] = 0.0f;
  int wave = tid >> 6, lane = tid & 63;
  int row = blockIdx.x * 4 + wave;
  const float* src = (row < HALF_N) ? (zi + (size_t)row * DIM)
                                    : (zj + (size_t)(row - HALF_N) * DIM);
  const float4* s4 = (const float4*)src;
  float4 a = s4[lane];
  float4 b = s4[lane + 64];
  float ss = a.x * a.x + a.y * a.y + a.z * a.z + a.w * a.w +
             b.x * b.x + b.y * b.y + b.z * b.z + b.w * b.w;
#pragma unroll
  for (int off = 32; off > 0; off >>= 1) ss += __shfl_xor(ss, off, 64);
  float nrm = fmaxf(sqrtf(ss), 1e-8f);
  float inv = 1.0f / nrm;
  uint2 oa, ob;
  oa.x = f2bf(a.x * inv) | (f2bf(a.y * inv) << 16);
  oa.y = f2bf(a.z * inv) | (f2bf(a.w * inv) << 16);
  ob.x = f2bf(b.x * inv) | (f2bf(b.y * inv) << 16);
  ob.y = f2bf(b.z * inv) | (f2bf(b.w * inv) << 16);
  unsigned short* dst = zn + (size_t)row * DIM;
  *((uint2*)(dst + lane * 4)) = oa;
  *((uint2*)(dst + 256 + lane * 4)) = ob;
}

// Upper-triangular 128x128 tiles only (sim is symmetric): off-diag tiles feed BOTH
// row-sums and col-sums. XOR-swizzled LDS (2-way = free). Explicit double buffer
// with post-barrier load issue so each vmcnt drain waits on loads one phase old.
__global__ void __launch_bounds__(256) k_simsum(const unsigned short* __restrict__ zn,
                                                float* __restrict__ sumexp,
                                                float* __restrict__ posv) {
  __shared__ __align__(16) unsigned short As[2][128 * 32];  // 2 x 8 KB
  __shared__ __align__(16) unsigned short Bs[2][128 * 32];  // 2 x 8 KB
  int tid = threadIdx.x;
  int wave = tid >> 6, lane = tid & 63;

  // triangular decode, tn-major: idx = tn(tn+1)/2 + tm, tm <= tn
  int idx = blockIdx.x;
  int tn = (int)((sqrtf(8.0f * idx + 1.0f) - 1.0f) * 0.5f);
  while (tn * (tn + 1) / 2 > idx) tn--;
  while ((tn + 1) * (tn + 2) / 2 <= idx) tn++;
  int tm = idx - tn * (tn + 1) / 2;
  int rowBase = tm * 128, colBase = tn * 128;
  int wr = (wave >> 1) * 64, wc = (wave & 1) * 64;  // wave's 64x64 quadrant
  int r15 = lane & 15, q = lane >> 4;

  // staging: wave w copies 32 rows of A-tile and B-tile; 16B/lane.
  // Source k-chunk XOR-swizzled by ((row>>1)&3); invariant under row+16.
  int rA = wave * 32 + (lane >> 2);
  int swzS = (rA >> 1) & 3;
  int c8 = ((lane & 3) ^ swzS) * 8;
  const unsigned short* gA0 = zn + (size_t)(rowBase + rA) * DIM + c8;
  const unsigned short* gA1 = gA0 + 16 * DIM;
  const unsigned short* gB0 = zn + (size_t)(colBase + rA) * DIM + c8;
  const unsigned short* gB1 = gB0 + 16 * DIM;
  unsigned short* lA[2] = {&As[0][wave * 1024], &As[1][wave * 1024]};
  unsigned short* lB[2] = {&Bs[0][wave * 1024], &Bs[1][wave * 1024]};

#define STAGE(b)                         \
  do {                                   \
    gload_lds16(gA0, lA[b]);             \
    gload_lds16(gA1, lA[b] + 512);       \
    gload_lds16(gB0, lB[b]);             \
    gload_lds16(gB1, lB[b] + 512);       \
    gA0 += 32; gA1 += 32; gB0 += 32; gB1 += 32; \
  } while (0)

  f32x4 acc[4][4];
#pragma unroll
  for (int i = 0; i < 4; i++)
#pragma unroll
    for (int j = 0; j < 4; j++) acc[i][j] = (f32x4){0.f, 0.f, 0.f, 0.f};

  int swzR = (r15 >> 1) & 3;
  int aIdx0 = (wr + r15) * 4 + (q ^ swzR);  // + 64 per 16-row step
  int bIdx0 = (wc + r15) * 4 + (q ^ swzR);

#define COMPUTE(b)                                                               \
  do {                                                                           \
    const bf16x8* Av = (const bf16x8*)As[b];                                     \
    const bf16x8* Bv = (const bf16x8*)Bs[b];                                     \
    bf16x8 af[4], bfr[4];                                                        \
    _Pragma("unroll") for (int i = 0; i < 4; i++) af[i] = Av[aIdx0 + i * 64];    \
    _Pragma("unroll") for (int j = 0; j < 4; j++) bfr[j] = Bv[bIdx0 + j * 64];   \
    _Pragma("unroll") for (int i = 0; i < 4; i++)                                \
      _Pragma("unroll") for (int j = 0; j < 4; j++)                              \
        acc[i][j] = __builtin_amdgcn_mfma_f32_16x16x32_bf16(af[i], bfr[j], acc[i][j], 0, 0, 0); \
  } while (0)

  STAGE(0);  // prologue: tile 0
#pragma unroll
  for (int s = 0; s < 16; s += 2) {
    __syncthreads();            // drains tile-s loads (issued one phase ago)
    if (s + 1 < 16) STAGE(1);   // issue tile s+1 BEFORE compute phase
    COMPUTE(0);
    __syncthreads();            // drains tile-(s+1) loads
    if (s + 2 < 16) STAGE(0);   // issue tile s+2
    COMPUTE(1);
  }

  // Epilogue. C/D layout: col = lane&15, row = q*4 + reg.
  bool isDiag = (tm == tn);
  bool hasPos = (tn == tm + 32);
  int gr0 = rowBase + wr + q * 4;
  int gc0 = colBase + wc + r15;
  float rs[16], cs[4];
#pragma unroll
  for (int t = 0; t < 16; t++) rs[t] = 0.f;
#pragma unroll
  for (int t = 0; t < 4; t++) cs[t] = 0.f;
#pragma unroll
  for (int i = 0; i < 4; i++) {
#pragma unroll
    for (int j = 0; j < 4; j++) {
#pragma unroll
      for (int r = 0; r < 4; r++) {
        float s = acc[i][j][r] * INV_TEMP;
        int gr = gr0 + i * 16 + r;
        int gc = gc0 + j * 16;
        if (hasPos && gc == gr + HALF_N) { posv[gr] = s; posv[gc] = s; }
        float e = __expf(s);
        if (isDiag && gc == gr) e = 0.f;
        rs[i * 4 + r] += e;
        cs[j] += e;
      }
    }
  }
  // Fold-reduce rs[16] across the 16-lane r15 group; lane ends holding rs[r15] fully
  // reduced. 15 shfl total instead of 64.
#pragma unroll
  for (int t = 0; t < 8; t++) {
    float mine = (lane & 8) ? rs[t + 8] : rs[t];
    float oth = __shfl_xor((lane & 8) ? rs[t] : rs[t + 8], 8, 64);
    rs[t] = mine + oth;
  }
#pragma unroll
  for (int t = 0; t < 4; t++) {
    float mine = (lane & 4) ? rs[t + 4] : rs[t];
    float oth = __shfl_xor((lane & 4) ? rs[t] : rs[t + 4], 4, 64);
    rs[t] = mine + oth;
  }
#pragma unroll
  for (int t = 0; t < 2; t++) {
    float mine = (lane & 2) ? rs[t + 2] : rs[t];
    float oth = __shfl_xor((lane & 2) ? rs[t] : rs[t + 2], 2, 64);
    rs[t] = mine + oth;
  }
  {
    float mine = (lane & 1) ? rs[1] : rs[0];
    float oth = __shfl_xor((lane & 1) ? rs[0] : rs[1], 1, 64);
    rs[0] = mine + oth;
  }
  int myrow = rowBase + wr + q * 4 + ((r15 >> 2) * 16) + (r15 & 3);
  atomicAdd(&sumexp[myrow], rs[0]);

  if (!isDiag) {
    // Fold-reduce cs[4] across the 4 q-groups (lane bits 4,5); lane ends with cs for
    // col j = 2*bit4 + bit5. One atomic per lane.
#pragma unroll
    for (int t = 0; t < 2; t++) {
      float mine = (lane & 16) ? cs[t + 2] : cs[t];
      float oth = __shfl_xor((lane & 16) ? cs[t] : cs[t + 2], 16, 64);
      cs[t] = mine + oth;
    }
    {
      float mine = (lane & 32) ? cs[1] : cs[0];
      float oth = __shfl_xor((lane & 32) ? cs[0] : cs[1], 32, 64);
      cs[0] = mine + oth;
    }
    int myj = 2 * ((lane >> 4) & 1) + ((lane >> 5) & 1);
    atomicAdd(&sumexp[colBase + wc + myj * 16 + r15], cs[0]);
  }
#undef STAGE
#undef COMPUTE
}

__global__ void __launch_bounds__(1024) k_final(const float* __restrict__ sumexp,
                                                const float* __restrict__ posv,
                                                float* __restrict__ out) {
  __shared__ float red[16];
  int tid = threadIdx.x;
  const float4* se4 = (const float4*)sumexp;
  const float4* pv4 = (const float4*)posv;
  float p = 0.f;
#pragma unroll
  for (int c = 0; c < 2; c++) {
    float4 se = se4[tid * 2 + c];
    float4 pv = pv4[tid * 2 + c];
    p += (__logf(se.x) - pv.x) + (__logf(se.y) - pv.y) +
         (__logf(se.z) - pv.z) + (__logf(se.w) - pv.w);
  }
#pragma unroll
  for (int off = 32; off > 0; off >>= 1) p += __shfl_xor(p, off, 64);
  int wv = tid >> 6, ln = tid & 63;
  if (ln == 0) red[wv] = p;
  __syncthreads();
  if (tid == 0) {
    float t = 0.f;
    for (int w = 0; w < 16; w++) t += red[w];
    out[0] = t / (float)NROWS;
  }
}

extern "C" void kernel_launch(void* const* d_in, const int* in_sizes, int n_in,
                              void* d_out, int out_size, void* d_ws, size_t ws_size,
                              hipStream_t stream) {
  const float* zi = (const float*)d_in[0];
  const float* zj = (const float*)d_in[1];
  unsigned short* zn = (unsigned short*)d_ws;                         // 8 MB
  float* sumexp = (float*)((char*)d_ws + (size_t)NROWS * DIM * 2);    // 32 KB
  float* posv = sumexp + NROWS;                                       // 32 KB
  float* out = (float*)d_out;

  hipLaunchKernelGGL(k_normalize, dim3(2048), dim3(256), 0, stream, zi, zj, zn, sumexp);
  hipLaunchKernelGGL(k_simsum, dim3(2080), dim3(256), 0, stream, zn, sumexp, posv);
  hipLaunchKernelGGL(k_final, dim3(1), dim3(1024), 0, stream, sumexp, posv, out);
}